// Round 1
// baseline (526.558 us; speedup 1.0000x reference)
//
#include <hip/hip_runtime.h>
#include <math.h>

#define BB 1024
#define TT 64
#define DD 256
#define PP 2048
#define HH 512

// ---------------- block reduction helper (256 threads) ----------------
__device__ __forceinline__ float blk_reduce(float v, float* sm) {
    int tid = threadIdx.x;
    #pragma unroll
    for (int o = 32; o > 0; o >>= 1) v += __shfl_down(v, o, 64);
    if ((tid & 63) == 0) sm[tid >> 6] = v;
    __syncthreads();
    float r = sm[0] + sm[1] + sm[2] + sm[3];
    __syncthreads();
    return r;
}

// ---------------- mean over T + row norm ----------------
// one block (256 threads) per row; x is [rows, T, D]
__global__ void reduce_bt(const float* __restrict__ x, float* __restrict__ cent,
                          float* __restrict__ nrm) {
    __shared__ float sm[4];
    int r = blockIdx.x, d = threadIdx.x;
    const float* p = x + (size_t)r * TT * DD + d;
    float s = 0.f;
    #pragma unroll
    for (int t = 0; t < TT; ++t) s += p[t * DD];
    float m = s * (1.f / TT);
    cent[(size_t)r * DD + d] = m;
    float tot = blk_reduce(m * m, sm);
    if (d == 0) nrm[r] = fmaxf(sqrtf(tot), 1e-8f);
}

// ---------------- global mean of feat_flat over B ----------------
__global__ void gmean_k(const float* __restrict__ ff, float* __restrict__ gmean) {
    int d = threadIdx.x;
    int b0 = blockIdx.x * 32;
    float s = 0.f;
    for (int b = b0; b < b0 + 32; ++b) s += ff[(size_t)b * DD + d];
    atomicAdd(&gmean[d], s * (1.f / BB));
}

// ---------------- addvec[j] = dd_b1[j] + sum_k gmean[k]*dd_w1[256+k][j] ----------------
__global__ void addvec_k(const float* __restrict__ gmean, const float* __restrict__ w1,
                         const float* __restrict__ b1, float* __restrict__ av) {
    int j = (blockIdx.x & 1) * 256 + threadIdx.x;
    int k0 = (blockIdx.x >> 1) * 64;
    float s = 0.f;
    for (int k = k0; k < k0 + 64; ++k) s += gmean[k] * w1[(size_t)(DD + k) * HH + j];
    if (k0 == 0) s += b1[j];
    atomicAdd(&av[j], s);
}

// ---------------- sim GEMM (NT): drift = 1 - (FF·PC^T)/(fn pn), + column sums ----------------
__global__ void sim_gemm(const float* __restrict__ FF, const float* __restrict__ PC,
                         const float* __restrict__ fn, const float* __restrict__ pn,
                         float* __restrict__ drift, float* __restrict__ colsum) {
    __shared__ float As[16][68];
    __shared__ float Bs[16][68];
    __shared__ float cs[16][64];
    int tid = threadIdx.x;
    int bm = blockIdx.y * 64;   // b
    int bn = blockIdx.x * 64;   // p
    int am = tid >> 2, aq = (tid & 3) << 2;
    int ty = tid >> 4, tx = tid & 15;
    float acc[4][4] = {{0.f}};
    for (int k0 = 0; k0 < DD; k0 += 16) {
        float4 av = *(const float4*)(FF + (size_t)(bm + am) * DD + k0 + aq);
        float4 bv = *(const float4*)(PC + (size_t)(bn + am) * DD + k0 + aq);
        As[aq + 0][am] = av.x; As[aq + 1][am] = av.y; As[aq + 2][am] = av.z; As[aq + 3][am] = av.w;
        Bs[aq + 0][am] = bv.x; Bs[aq + 1][am] = bv.y; Bs[aq + 2][am] = bv.z; Bs[aq + 3][am] = bv.w;
        __syncthreads();
        #pragma unroll
        for (int k = 0; k < 16; ++k) {
            float4 a = *(const float4*)&As[k][ty * 4];
            float4 w = *(const float4*)&Bs[k][tx * 4];
            acc[0][0] = fmaf(a.x, w.x, acc[0][0]); acc[0][1] = fmaf(a.x, w.y, acc[0][1]);
            acc[0][2] = fmaf(a.x, w.z, acc[0][2]); acc[0][3] = fmaf(a.x, w.w, acc[0][3]);
            acc[1][0] = fmaf(a.y, w.x, acc[1][0]); acc[1][1] = fmaf(a.y, w.y, acc[1][1]);
            acc[1][2] = fmaf(a.y, w.z, acc[1][2]); acc[1][3] = fmaf(a.y, w.w, acc[1][3]);
            acc[2][0] = fmaf(a.z, w.x, acc[2][0]); acc[2][1] = fmaf(a.z, w.y, acc[2][1]);
            acc[2][2] = fmaf(a.z, w.z, acc[2][2]); acc[2][3] = fmaf(a.z, w.w, acc[2][3]);
            acc[3][0] = fmaf(a.w, w.x, acc[3][0]); acc[3][1] = fmaf(a.w, w.y, acc[3][1]);
            acc[3][2] = fmaf(a.w, w.z, acc[3][2]); acc[3][3] = fmaf(a.w, w.w, acc[3][3]);
        }
        __syncthreads();
    }
    float csl[4] = {0.f, 0.f, 0.f, 0.f};
    #pragma unroll
    for (int r = 0; r < 4; ++r) {
        int row = bm + ty * 4 + r;
        float fi = 1.f / fn[row];
        #pragma unroll
        for (int c = 0; c < 4; ++c) {
            int col = bn + tx * 4 + c;
            float s = acc[r][c] * fi / pn[col];
            float dr = 1.f - s;
            drift[(size_t)row * PP + col] = dr;
            csl[c] += dr;
        }
    }
    #pragma unroll
    for (int c = 0; c < 4; ++c) cs[ty][tx * 4 + c] = csl[c];
    __syncthreads();
    if (tid < 64) {
        float s = 0.f;
        #pragma unroll
        for (int g = 0; g < 16; ++g) s += cs[g][tid];
        atomicAdd(&colsum[bn + tid], s);
    }
}

// ---------------- generic tiled GEMM NN: C = A[M,K] @ W[K,N](ldw) + bias, opt relu ----------------
template <int RELU>
__global__ void gemm_nn(const float* __restrict__ A, const float* __restrict__ W,
                        const float* __restrict__ bias, float* __restrict__ C,
                        int M, int N, int K, int ldw) {
    __shared__ float As[16][68];
    __shared__ float Ws[16][68];
    int tid = threadIdx.x;
    int bm = blockIdx.y * 64, bn = blockIdx.x * 64;
    int am = tid >> 2, aq = (tid & 3) << 2;
    int wk = tid >> 4, wq = (tid & 15) << 2;
    int ty = tid >> 4, tx = tid & 15;
    float acc[4][4] = {{0.f}};
    for (int k0 = 0; k0 < K; k0 += 16) {
        float4 av = *(const float4*)(A + (size_t)(bm + am) * K + k0 + aq);
        float4 wv = *(const float4*)(W + (size_t)(k0 + wk) * ldw + bn + wq);
        As[aq + 0][am] = av.x; As[aq + 1][am] = av.y; As[aq + 2][am] = av.z; As[aq + 3][am] = av.w;
        *(float4*)&Ws[wk][wq] = wv;
        __syncthreads();
        #pragma unroll
        for (int k = 0; k < 16; ++k) {
            float4 a = *(const float4*)&As[k][ty * 4];
            float4 w = *(const float4*)&Ws[k][tx * 4];
            acc[0][0] = fmaf(a.x, w.x, acc[0][0]); acc[0][1] = fmaf(a.x, w.y, acc[0][1]);
            acc[0][2] = fmaf(a.x, w.z, acc[0][2]); acc[0][3] = fmaf(a.x, w.w, acc[0][3]);
            acc[1][0] = fmaf(a.y, w.x, acc[1][0]); acc[1][1] = fmaf(a.y, w.y, acc[1][1]);
            acc[1][2] = fmaf(a.y, w.z, acc[1][2]); acc[1][3] = fmaf(a.y, w.w, acc[1][3]);
            acc[2][0] = fmaf(a.z, w.x, acc[2][0]); acc[2][1] = fmaf(a.z, w.y, acc[2][1]);
            acc[2][2] = fmaf(a.z, w.z, acc[2][2]); acc[2][3] = fmaf(a.z, w.w, acc[2][3]);
            acc[3][0] = fmaf(a.w, w.x, acc[3][0]); acc[3][1] = fmaf(a.w, w.y, acc[3][1]);
            acc[3][2] = fmaf(a.w, w.z, acc[3][2]); acc[3][3] = fmaf(a.w, w.w, acc[3][3]);
        }
        __syncthreads();
    }
    #pragma unroll
    for (int r = 0; r < 4; ++r) {
        int row = bm + ty * 4 + r;
        #pragma unroll
        for (int c = 0; c < 4; ++c) {
            int col = bn + tx * 4 + c;
            float v = acc[r][c] + bias[col];
            if (RELU) v = fmaxf(v, 0.f);
            C[(size_t)row * N + col] = v;
        }
    }
}

// ---------------- layernorm (width 512) + relu, in place ----------------
__global__ void ln_relu(float* __restrict__ X, const float* __restrict__ g,
                        const float* __restrict__ be) {
    __shared__ float sm[4];
    int r = blockIdx.x, tid = threadIdx.x;
    float* row = X + (size_t)r * HH;
    float x0 = row[tid], x1 = row[tid + 256];
    float mu = blk_reduce(x0 + x1, sm) * (1.f / HH);
    float d0 = x0 - mu, d1 = x1 - mu;
    float var = blk_reduce(d0 * d0 + d1 * d1, sm) * (1.f / HH);
    float rs = rsqrtf(var + 1e-5f);
    float y0 = d0 * rs * g[tid] + be[tid];
    float y1 = d1 * rs * g[tid + 256] + be[tid + 256];
    row[tid] = fmaxf(y0, 0.f);
    row[tid + 256] = fmaxf(y1, 0.f);
}

// ---------------- drift_conf -> strength, and is_drifted output ----------------
__global__ void conf_k(const float* __restrict__ h2, const float* __restrict__ w3,
                       const float* __restrict__ b3, const float* __restrict__ colsum,
                       float* __restrict__ strength, float* __restrict__ out_is) {
    __shared__ float sm[4];
    int p = blockIdx.x, tid = threadIdx.x;
    float v = h2[(size_t)p * 256 + tid] * w3[tid];
    float s = blk_reduce(v, sm);
    if (tid == 0) {
        float conf = 1.f / (1.f + expf(-(s + b3[0])));
        float st = fminf(fmaxf(0.1f * conf, 0.f), 0.5f);
        strength[p] = st;
        out_is[p] = (colsum[p] * (1.f / BB) > 0.3f) ? 1.f : 0.f;
    }
}

// ---------------- write calibrated [P,T,D] ----------------
__global__ void finalize_k(const float* __restrict__ pc, const float* __restrict__ delta,
                           const float* __restrict__ strength, const float* __restrict__ colsum,
                           const float* __restrict__ proto, float* __restrict__ out) {
    int p = blockIdx.x, d = threadIdx.x;
    bool dr = colsum[p] * (1.f / BB) > 0.3f;
    float* o = out + (size_t)p * TT * DD + d;
    if (dr) {
        float nc = pc[(size_t)p * DD + d] + strength[p] * delta[(size_t)p * DD + d];
        #pragma unroll 4
        for (int t = 0; t < TT; ++t) o[t * DD] = nc;
    } else {
        const float* pr = proto + (size_t)p * TT * DD + d;
        #pragma unroll 4
        for (int t = 0; t < TT; ++t) o[t * DD] = pr[t * DD];
    }
}

extern "C" void kernel_launch(void* const* d_in, const int* in_sizes, int n_in,
                              void* d_out, int out_size, void* d_ws, size_t ws_size,
                              hipStream_t stream) {
    const float* cf    = (const float*)d_in[0];   // [B,T,D]
    const float* proto = (const float*)d_in[1];   // [P,T,D]
    const float* dd_w1 = (const float*)d_in[2];   // [512,512]
    const float* dd_b1 = (const float*)d_in[3];
    const float* dd_g1 = (const float*)d_in[4];
    const float* dd_be1= (const float*)d_in[5];
    const float* dd_w2 = (const float*)d_in[6];   // [512,256]
    const float* dd_b2 = (const float*)d_in[7];
    const float* dd_w3 = (const float*)d_in[8];   // [256,1]
    const float* dd_b3 = (const float*)d_in[9];
    const float* cal_w1= (const float*)d_in[10];  // [256,512]
    const float* cal_b1= (const float*)d_in[11];
    const float* cal_g1= (const float*)d_in[12];
    const float* cal_be1=(const float*)d_in[13];
    const float* cal_w2= (const float*)d_in[14];  // [512,512]
    const float* cal_b2= (const float*)d_in[15];
    const float* cal_w3= (const float*)d_in[16];  // [512,256]
    const float* cal_b3= (const float*)d_in[17];

    float* out_cal   = (float*)d_out;                         // P*T*D
    float* out_drift = out_cal + (size_t)PP * TT * DD;        // B*P
    float* out_is    = out_drift + (size_t)BB * PP;           // P

    float* w = (float*)d_ws;
    float* gmean    = w;             // 256
    float* colsum   = w + 256;       // 2048
    float* addvec   = w + 2304;      // 512
    float* fn       = w + 2816;      // 1024
    float* pn       = w + 3840;      // 2048
    float* strength = w + 5888;      // 2048
    float* ff       = w + 8192;      // 1024*256
    float* pc       = w + 270336;    // 2048*256
    float* buf1     = w + 794624;    // 2048*512
    float* buf2     = w + 1843200;   // 2048*256
    float* buf3     = w + 2367488;   // 2048*512

    // zero accumulators (gmean + colsum + addvec)
    hipMemsetAsync(d_ws, 0, 2816 * sizeof(float), stream);

    reduce_bt<<<BB, 256, 0, stream>>>(cf, ff, fn);
    reduce_bt<<<PP, 256, 0, stream>>>(proto, pc, pn);
    gmean_k<<<32, 256, 0, stream>>>(ff, gmean);
    addvec_k<<<8, 256, 0, stream>>>(gmean, dd_w1, dd_b1, addvec);

    sim_gemm<<<dim3(PP / 64, BB / 64), 256, 0, stream>>>(ff, pc, fn, pn, out_drift, colsum);

    // drift-detector MLP
    gemm_nn<0><<<dim3(HH / 64, PP / 64), 256, 0, stream>>>(pc, dd_w1, addvec, buf1,
                                                           PP, HH, DD, HH);
    ln_relu<<<PP, 256, 0, stream>>>(buf1, dd_g1, dd_be1);
    gemm_nn<1><<<dim3(256 / 64, PP / 64), 256, 0, stream>>>(buf1, dd_w2, dd_b2, buf2,
                                                            PP, 256, HH, 256);
    conf_k<<<PP, 256, 0, stream>>>(buf2, dd_w3, dd_b3, colsum, strength, out_is);

    // calibration MLP
    gemm_nn<0><<<dim3(HH / 64, PP / 64), 256, 0, stream>>>(pc, cal_w1, cal_b1, buf1,
                                                           PP, HH, DD, HH);
    ln_relu<<<PP, 256, 0, stream>>>(buf1, cal_g1, cal_be1);
    gemm_nn<1><<<dim3(HH / 64, PP / 64), 256, 0, stream>>>(buf1, cal_w2, cal_b2, buf3,
                                                           PP, HH, HH, HH);
    gemm_nn<0><<<dim3(256 / 64, PP / 64), 256, 0, stream>>>(buf3, cal_w3, cal_b3, buf2,
                                                            PP, 256, HH, 256);

    finalize_k<<<PP, 256, 0, stream>>>(pc, buf2, strength, colsum, proto, out_cal);
}

// Round 2
// 418.121 us; speedup vs baseline: 1.2593x; 1.2593x over previous
//
#include <hip/hip_runtime.h>
#include <hip/hip_bf16.h>
#include <math.h>

#define BB 1024
#define TT 64
#define DD 256
#define PP 2048
#define HH 512

typedef __attribute__((ext_vector_type(8))) short short8;
typedef __attribute__((ext_vector_type(4))) float f32x4;

// ---------------- block reduction helper (256 threads) ----------------
__device__ __forceinline__ float blk_reduce(float v, float* sm) {
    int tid = threadIdx.x;
    #pragma unroll
    for (int o = 32; o > 0; o >>= 1) v += __shfl_down(v, o, 64);
    if ((tid & 63) == 0) sm[tid >> 6] = v;
    __syncthreads();
    float r = sm[0] + sm[1] + sm[2] + sm[3];
    __syncthreads();
    return r;
}

// ---------------- mean over T + row norm; emits fp32 + bf16 centers ----------------
__global__ void reduce_bt(const float* __restrict__ x, float* __restrict__ cent,
                          __hip_bfloat16* __restrict__ centb, float* __restrict__ nrm) {
    __shared__ float sm[4];
    int r = blockIdx.x, d = threadIdx.x;
    const float* p = x + (size_t)r * TT * DD + d;
    float s = 0.f;
    #pragma unroll
    for (int t = 0; t < TT; ++t) s += p[t * DD];
    float m = s * (1.f / TT);
    cent[(size_t)r * DD + d] = m;
    centb[(size_t)r * DD + d] = __float2bfloat16(m);
    float tot = blk_reduce(m * m, sm);
    if (d == 0) nrm[r] = fmaxf(sqrtf(tot), 1e-8f);
}

// ---------------- global mean of feat_flat over B ----------------
__global__ void gmean_k(const float* __restrict__ ff, float* __restrict__ gmean) {
    int d = threadIdx.x;
    int b0 = blockIdx.x * 32;
    float s = 0.f;
    for (int b = b0; b < b0 + 32; ++b) s += ff[(size_t)b * DD + d];
    atomicAdd(&gmean[d], s * (1.f / BB));
}

// ---------------- addvec[j] = dd_b1[j] + sum_k gmean[k]*dd_w1[256+k][j] ----------------
__global__ void addvec_k(const float* __restrict__ gmean, const float* __restrict__ w1,
                         const float* __restrict__ b1, float* __restrict__ av) {
    int j = (blockIdx.x & 1) * 256 + threadIdx.x;
    int k0 = (blockIdx.x >> 1) * 64;
    float s = 0.f;
    for (int k = k0; k < k0 + 64; ++k) s += gmean[k] * w1[(size_t)(DD + k) * HH + j];
    if (k0 == 0) s += b1[j];
    atomicAdd(&av[j], s);
}

// ---------------- convert 5 weight matrices to bf16, transposed [N][K] ----------------
__global__ void cvt_all(const float* __restrict__ dd_w1, const float* __restrict__ dd_w2,
                        const float* __restrict__ cal_w1, const float* __restrict__ cal_w2,
                        const float* __restrict__ cal_w3,
                        __hip_bfloat16* __restrict__ t1, __hip_bfloat16* __restrict__ t2,
                        __hip_bfloat16* __restrict__ t3, __hip_bfloat16* __restrict__ t4,
                        __hip_bfloat16* __restrict__ t5) {
    int b = blockIdx.x, tid = threadIdx.x;
    const float* src; __hip_bfloat16* dst; int K, N, base;
    if (b < 512)       { src = dd_w1;  dst = t1; K = 256; N = 512; base = 0; }
    else if (b < 1024) { src = dd_w2;  dst = t2; K = 512; N = 256; base = 512; }
    else if (b < 1536) { src = cal_w1; dst = t3; K = 256; N = 512; base = 1024; }
    else if (b < 2560) { src = cal_w2; dst = t4; K = 512; N = 512; base = 1536; }
    else               { src = cal_w3; dst = t5; K = 512; N = 256; base = 2560; }
    int idx = (b - base) * 256 + tid;
    int n = idx & (N - 1);
    int k = idx >> ((N == 512) ? 9 : 8);
    dst[(size_t)n * K + k] = __float2bfloat16(src[(size_t)k * N + n]);
}

// ---------------- sim MFMA: drift = 1 - (A·Bt)/(fn pn), + column sums ----------------
// A = ffb [1024,256] bf16, Bt = pcb [2048,256] bf16. One wave per 32x32 tile.
__global__ void sim_mfma(const __hip_bfloat16* __restrict__ A,
                         const __hip_bfloat16* __restrict__ Bt,
                         const float* __restrict__ fn, const float* __restrict__ pn,
                         float* __restrict__ drift, float* __restrict__ colsum) {
    int wid = ((blockIdx.x << 8) + threadIdx.x) >> 6;   // 0..2047
    int lane = threadIdx.x & 63;
    int mw = wid >> 6, nw = wid & 63;                   // 32 x 64 tiles
    int m0 = mw << 5, n0 = nw << 5;
    int lr = lane & 15, quad = lane >> 4;
    const __hip_bfloat16* pa0 = A + (size_t)(m0 + lr) * DD + quad * 8;
    const __hip_bfloat16* pa1 = pa0 + 16 * DD;
    const __hip_bfloat16* pb0 = Bt + (size_t)(n0 + lr) * DD + quad * 8;
    const __hip_bfloat16* pb1 = pb0 + 16 * DD;
    f32x4 acc00 = {0,0,0,0}, acc01 = {0,0,0,0}, acc10 = {0,0,0,0}, acc11 = {0,0,0,0};
    #pragma unroll
    for (int k = 0; k < DD; k += 32) {
        short8 a0 = *(const short8*)(pa0 + k);
        short8 a1 = *(const short8*)(pa1 + k);
        short8 b0 = *(const short8*)(pb0 + k);
        short8 b1 = *(const short8*)(pb1 + k);
        acc00 = __builtin_amdgcn_mfma_f32_16x16x32_bf16(a0, b0, acc00, 0, 0, 0);
        acc01 = __builtin_amdgcn_mfma_f32_16x16x32_bf16(a0, b1, acc01, 0, 0, 0);
        acc10 = __builtin_amdgcn_mfma_f32_16x16x32_bf16(a1, b0, acc10, 0, 0, 0);
        acc11 = __builtin_amdgcn_mfma_f32_16x16x32_bf16(a1, b1, acc11, 0, 0, 0);
    }
    int col0 = n0 + lr, col1 = col0 + 16;
    float ip0 = 1.f / pn[col0], ip1 = 1.f / pn[col1];
    float cs0 = 0.f, cs1 = 0.f;
    #pragma unroll
    for (int r = 0; r < 4; ++r) {
        int row0 = m0 + quad * 4 + r;
        int row1 = row0 + 16;
        float if0 = 1.f / fn[row0];
        float if1 = 1.f / fn[row1];
        float d00 = 1.f - acc00[r] * if0 * ip0;
        float d01 = 1.f - acc01[r] * if0 * ip1;
        float d10 = 1.f - acc10[r] * if1 * ip0;
        float d11 = 1.f - acc11[r] * if1 * ip1;
        drift[(size_t)row0 * PP + col0] = d00;
        drift[(size_t)row0 * PP + col1] = d01;
        drift[(size_t)row1 * PP + col0] = d10;
        drift[(size_t)row1 * PP + col1] = d11;
        cs0 += d00 + d10;
        cs1 += d01 + d11;
    }
    cs0 += __shfl_xor(cs0, 16, 64); cs0 += __shfl_xor(cs0, 32, 64);
    cs1 += __shfl_xor(cs1, 16, 64); cs1 += __shfl_xor(cs1, 32, 64);
    if (quad == 0) {
        atomicAdd(&colsum[col0], cs0);
        atomicAdd(&colsum[col1], cs1);
    }
}

// ---------------- MFMA GEMM: C[M=2048,N] = A[M,K]·Bt[N,K]^T + bias ----------------
// One wave per 32x32 output tile; fragments loaded straight from global (L2-resident).
template <int K, int OUT_BF16, int RELU>
__global__ void gemm_mfma(const __hip_bfloat16* __restrict__ A,
                          const __hip_bfloat16* __restrict__ Bt,
                          const float* __restrict__ bias,
                          void* __restrict__ Cout, int N) {
    int wid = ((blockIdx.x << 8) + threadIdx.x) >> 6;
    int lane = threadIdx.x & 63;
    int nt = N >> 5;
    int mw = wid / nt, nw = wid - mw * nt;
    int m0 = mw << 5, n0 = nw << 5;
    int lr = lane & 15, quad = lane >> 4;
    const __hip_bfloat16* pa0 = A + (size_t)(m0 + lr) * K + quad * 8;
    const __hip_bfloat16* pa1 = pa0 + 16 * K;
    const __hip_bfloat16* pb0 = Bt + (size_t)(n0 + lr) * K + quad * 8;
    const __hip_bfloat16* pb1 = pb0 + 16 * K;
    f32x4 acc00 = {0,0,0,0}, acc01 = {0,0,0,0}, acc10 = {0,0,0,0}, acc11 = {0,0,0,0};
    #pragma unroll
    for (int k = 0; k < K; k += 32) {
        short8 a0 = *(const short8*)(pa0 + k);
        short8 a1 = *(const short8*)(pa1 + k);
        short8 b0 = *(const short8*)(pb0 + k);
        short8 b1 = *(const short8*)(pb1 + k);
        acc00 = __builtin_amdgcn_mfma_f32_16x16x32_bf16(a0, b0, acc00, 0, 0, 0);
        acc01 = __builtin_amdgcn_mfma_f32_16x16x32_bf16(a0, b1, acc01, 0, 0, 0);
        acc10 = __builtin_amdgcn_mfma_f32_16x16x32_bf16(a1, b0, acc10, 0, 0, 0);
        acc11 = __builtin_amdgcn_mfma_f32_16x16x32_bf16(a1, b1, acc11, 0, 0, 0);
    }
    int col0 = n0 + lr, col1 = col0 + 16;
    float bi0 = bias[col0], bi1 = bias[col1];
    #pragma unroll
    for (int r = 0; r < 4; ++r) {
        int row0 = m0 + quad * 4 + r;
        int row1 = row0 + 16;
        float v00 = acc00[r] + bi0, v01 = acc01[r] + bi1;
        float v10 = acc10[r] + bi0, v11 = acc11[r] + bi1;
        if (RELU) {
            v00 = fmaxf(v00, 0.f); v01 = fmaxf(v01, 0.f);
            v10 = fmaxf(v10, 0.f); v11 = fmaxf(v11, 0.f);
        }
        if (OUT_BF16) {
            __hip_bfloat16* C = (__hip_bfloat16*)Cout;
            C[(size_t)row0 * N + col0] = __float2bfloat16(v00);
            C[(size_t)row0 * N + col1] = __float2bfloat16(v01);
            C[(size_t)row1 * N + col0] = __float2bfloat16(v10);
            C[(size_t)row1 * N + col1] = __float2bfloat16(v11);
        } else {
            float* C = (float*)Cout;
            C[(size_t)row0 * N + col0] = v00;
            C[(size_t)row0 * N + col1] = v01;
            C[(size_t)row1 * N + col0] = v10;
            C[(size_t)row1 * N + col1] = v11;
        }
    }
}

// ---------------- layernorm (width 512) + relu: fp32 in -> bf16 out ----------------
__global__ void ln_relu(const float* __restrict__ X, __hip_bfloat16* __restrict__ Y,
                        const float* __restrict__ g, const float* __restrict__ be) {
    __shared__ float sm[4];
    int r = blockIdx.x, tid = threadIdx.x;
    const float* row = X + (size_t)r * HH;
    float x0 = row[tid], x1 = row[tid + 256];
    float mu = blk_reduce(x0 + x1, sm) * (1.f / HH);
    float d0 = x0 - mu, d1 = x1 - mu;
    float var = blk_reduce(d0 * d0 + d1 * d1, sm) * (1.f / HH);
    float rs = rsqrtf(var + 1e-5f);
    float y0 = fmaxf(d0 * rs * g[tid] + be[tid], 0.f);
    float y1 = fmaxf(d1 * rs * g[tid + 256] + be[tid + 256], 0.f);
    __hip_bfloat16* yrow = Y + (size_t)r * HH;
    yrow[tid] = __float2bfloat16(y0);
    yrow[tid + 256] = __float2bfloat16(y1);
}

// ---------------- drift_conf -> strength, and is_drifted output ----------------
__global__ void conf_k(const __hip_bfloat16* __restrict__ h2, const float* __restrict__ w3,
                       const float* __restrict__ b3, const float* __restrict__ colsum,
                       float* __restrict__ strength, float* __restrict__ out_is) {
    __shared__ float sm[4];
    int p = blockIdx.x, tid = threadIdx.x;
    float v = __bfloat162float(h2[(size_t)p * 256 + tid]) * w3[tid];
    float s = blk_reduce(v, sm);
    if (tid == 0) {
        float conf = 1.f / (1.f + expf(-(s + b3[0])));
        float st = fminf(fmaxf(0.1f * conf, 0.f), 0.5f);
        strength[p] = st;
        out_is[p] = (colsum[p] * (1.f / BB) > 0.3f) ? 1.f : 0.f;
    }
}

// ---------------- write calibrated [P,T,D] ----------------
__global__ void finalize_k(const float* __restrict__ pc, const float* __restrict__ delta,
                           const float* __restrict__ strength, const float* __restrict__ colsum,
                           const float* __restrict__ proto, float* __restrict__ out) {
    int p = blockIdx.x, d = threadIdx.x;
    bool dr = colsum[p] * (1.f / BB) > 0.3f;
    float* o = out + (size_t)p * TT * DD + d;
    if (dr) {
        float nc = pc[(size_t)p * DD + d] + strength[p] * delta[(size_t)p * DD + d];
        #pragma unroll 4
        for (int t = 0; t < TT; ++t) o[t * DD] = nc;
    } else {
        const float* pr = proto + (size_t)p * TT * DD + d;
        #pragma unroll 4
        for (int t = 0; t < TT; ++t) o[t * DD] = pr[t * DD];
    }
}

extern "C" void kernel_launch(void* const* d_in, const int* in_sizes, int n_in,
                              void* d_out, int out_size, void* d_ws, size_t ws_size,
                              hipStream_t stream) {
    const float* cf     = (const float*)d_in[0];
    const float* proto  = (const float*)d_in[1];
    const float* dd_w1  = (const float*)d_in[2];
    const float* dd_b1  = (const float*)d_in[3];
    const float* dd_g1  = (const float*)d_in[4];
    const float* dd_be1 = (const float*)d_in[5];
    const float* dd_w2  = (const float*)d_in[6];
    const float* dd_b2  = (const float*)d_in[7];
    const float* dd_w3  = (const float*)d_in[8];
    const float* dd_b3  = (const float*)d_in[9];
    const float* cal_w1 = (const float*)d_in[10];
    const float* cal_b1 = (const float*)d_in[11];
    const float* cal_g1 = (const float*)d_in[12];
    const float* cal_be1= (const float*)d_in[13];
    const float* cal_w2 = (const float*)d_in[14];
    const float* cal_b2 = (const float*)d_in[15];
    const float* cal_w3 = (const float*)d_in[16];
    const float* cal_b3 = (const float*)d_in[17];

    float* out_cal   = (float*)d_out;
    float* out_drift = out_cal + (size_t)PP * TT * DD;
    float* out_is    = out_drift + (size_t)BB * PP;

    float* w = (float*)d_ws;
    float* gmean    = w;             // 256
    float* colsum   = w + 256;       // 2048
    float* addvec   = w + 2304;      // 512
    float* fn       = w + 2816;      // 1024
    float* pn       = w + 3840;      // 2048
    float* strength = w + 5888;      // 2048
    float* ff       = w + 8192;      // 1024*256
    float* pc       = w + 270336;    // 2048*256
    float* buf1     = w + 794624;    // 2048*512 fp32
    float* delta    = w + 1843200;   // 2048*256 fp32
    __hip_bfloat16* ffb     = (__hip_bfloat16*)(w + 2367488);  // 1024*256
    __hip_bfloat16* pcb     = ffb + 262144;                    // 2048*256
    __hip_bfloat16* w1t_dd  = pcb + 524288;                    // 512*256
    __hip_bfloat16* w2t_dd  = w1t_dd + 131072;                 // 256*512
    __hip_bfloat16* w1t_cal = w2t_dd + 131072;                 // 512*256
    __hip_bfloat16* w2t_cal = w1t_cal + 131072;                // 512*512
    __hip_bfloat16* w3t_cal = w2t_cal + 262144;                // 256*512
    __hip_bfloat16* act1b   = w3t_cal + 131072;                // 2048*512
    __hip_bfloat16* act3b   = act1b + 1048576;                 // 2048*512
    __hip_bfloat16* act2b   = act3b + 1048576;                 // 2048*256

    hipMemsetAsync(d_ws, 0, 2816 * sizeof(float), stream);

    reduce_bt<<<BB, 256, 0, stream>>>(cf, ff, ffb, fn);
    reduce_bt<<<PP, 256, 0, stream>>>(proto, pc, pcb, pn);
    gmean_k<<<32, 256, 0, stream>>>(ff, gmean);
    addvec_k<<<8, 256, 0, stream>>>(gmean, dd_w1, dd_b1, addvec);
    cvt_all<<<3072, 256, 0, stream>>>(dd_w1, dd_w2, cal_w1, cal_w2, cal_w3,
                                      w1t_dd, w2t_dd, w1t_cal, w2t_cal, w3t_cal);

    sim_mfma<<<512, 256, 0, stream>>>(ffb, pcb, fn, pn, out_drift, colsum);

    // drift-detector MLP
    gemm_mfma<256, 0, 0><<<256, 256, 0, stream>>>(pcb, w1t_dd, addvec, buf1, HH);
    ln_relu<<<PP, 256, 0, stream>>>(buf1, act1b, dd_g1, dd_be1);
    gemm_mfma<512, 1, 1><<<128, 256, 0, stream>>>(act1b, w2t_dd, dd_b2, act2b, 256);
    conf_k<<<PP, 256, 0, stream>>>(act2b, dd_w3, dd_b3, colsum, strength, out_is);

    // calibration MLP
    gemm_mfma<256, 0, 0><<<256, 256, 0, stream>>>(pcb, w1t_cal, cal_b1, buf1, HH);
    ln_relu<<<PP, 256, 0, stream>>>(buf1, act1b, cal_g1, cal_be1);
    gemm_mfma<512, 1, 1><<<256, 256, 0, stream>>>(act1b, w2t_cal, cal_b2, act3b, HH);
    gemm_mfma<512, 0, 0><<<128, 256, 0, stream>>>(act3b, w3t_cal, cal_b3, delta, 256);

    finalize_k<<<PP, 256, 0, stream>>>(pc, delta, strength, colsum, proto, out_cal);
}

// Round 4
// 417.885 us; speedup vs baseline: 1.2601x; 1.0006x over previous
//
#include <hip/hip_runtime.h>
#include <hip/hip_bf16.h>
#include <math.h>

#define BB 1024
#define TT 64
#define DD 256
#define PP 2048
#define HH 512

typedef __attribute__((ext_vector_type(8))) short short8;
typedef __attribute__((ext_vector_type(4))) float f32x4;

// ---------------- block reduction helper (256 threads) ----------------
__device__ __forceinline__ float blk_reduce(float v, float* sm) {
    int tid = threadIdx.x;
    #pragma unroll
    for (int o = 32; o > 0; o >>= 1) v += __shfl_down(v, o, 64);
    if ((tid & 63) == 0) sm[tid >> 6] = v;
    __syncthreads();
    float r = sm[0] + sm[1] + sm[2] + sm[3];
    __syncthreads();
    return r;
}

// ================ K1: prep — reductions + weight cvt, role by blockIdx ===========
__global__ void prep_k(const float* __restrict__ cf, const float* __restrict__ proto,
                       const float* __restrict__ dd_w1, const float* __restrict__ dd_w2,
                       const float* __restrict__ cal_w1, const float* __restrict__ cal_w2,
                       const float* __restrict__ cal_w3,
                       float* __restrict__ gmean8, float* __restrict__ fn,
                       float* __restrict__ pn, float* __restrict__ pc,
                       __hip_bfloat16* __restrict__ ffb, __hip_bfloat16* __restrict__ pcb,
                       __hip_bfloat16* __restrict__ w1cat, __hip_bfloat16* __restrict__ w2dd,
                       __hip_bfloat16* __restrict__ w2cal, __hip_bfloat16* __restrict__ w3cal) {
    __shared__ float sm[4];
    int b = blockIdx.x, tid = threadIdx.x;
    if (b < 1024) {                       // reduce current_feat row b
        const float* p = cf + (size_t)b * TT * DD + tid;
        float s = 0.f;
        #pragma unroll
        for (int t = 0; t < TT; ++t) s += p[t * DD];
        float m = s * (1.f / TT);
        ffb[(size_t)b * DD + tid] = __float2bfloat16(m);
        atomicAdd(&gmean8[(b & 7) * 256 + tid], m * (1.f / BB));
        float tot = blk_reduce(m * m, sm);
        if (tid == 0) fn[b] = fmaxf(sqrtf(tot), 1e-8f);
    } else if (b < 3072) {                // reduce prototype row
        int r = b - 1024;
        const float* p = proto + (size_t)r * TT * DD + tid;
        float s = 0.f;
        #pragma unroll
        for (int t = 0; t < TT; ++t) s += p[t * DD];
        float m = s * (1.f / TT);
        pc[(size_t)r * DD + tid] = m;
        pcb[(size_t)r * DD + tid] = __float2bfloat16(m);
        float tot = blk_reduce(m * m, sm);
        if (tid == 0) pn[r] = fmaxf(sqrtf(tot), 1e-8f);
    } else {                              // weight convert+transpose
        int idx = (b - 3072) * 256 + tid;
        if (idx < 262144) {               // w1cat: dd_w1 | cal_w1, K=256 N=512 each
            int half = idx >> 17;         // 0: dd, 1: cal
            int i = idx & 131071;
            int n = i & 511, k = i >> 9;
            const float* src = half ? cal_w1 : dd_w1;
            w1cat[(size_t)(half * 512 + n) * 256 + k] = __float2bfloat16(src[(size_t)k * 512 + n]);
        } else if (idx < 393216) {        // w2dd: K=512 N=256
            int i = idx - 262144;
            int n = i & 255, k = i >> 8;
            w2dd[(size_t)n * 512 + k] = __float2bfloat16(dd_w2[(size_t)k * 256 + n]);
        } else if (idx < 655360) {        // w2cal: K=512 N=512
            int i = idx - 393216;
            int n = i & 511, k = i >> 9;
            w2cal[(size_t)n * 512 + k] = __float2bfloat16(cal_w2[(size_t)k * 512 + n]);
        } else {                          // w3cal: K=512 N=256
            int i = idx - 655360;
            int n = i & 255, k = i >> 8;
            w3cal[(size_t)n * 512 + k] = __float2bfloat16(cal_w3[(size_t)k * 256 + n]);
        }
    }
}

// ================ K2: sim MFMA + addvec, role by blockIdx =====================
__global__ void sim_addvec_k(const __hip_bfloat16* __restrict__ A,
                             const __hip_bfloat16* __restrict__ Bt,
                             const float* __restrict__ fn, const float* __restrict__ pn,
                             const float* __restrict__ gmean8,
                             const float* __restrict__ dd_w1, const float* __restrict__ dd_b1,
                             float* __restrict__ drift, float* __restrict__ colsum,
                             float* __restrict__ addvec) {
    if (blockIdx.x >= 512) {              // addvec role: 2 blocks x 256 j's
        __shared__ float gmk[256];
        int tid = threadIdx.x;
        float g = 0.f;
        #pragma unroll
        for (int s = 0; s < 8; ++s) g += gmean8[s * 256 + tid];
        gmk[tid] = g;
        __syncthreads();
        int j = (blockIdx.x - 512) * 256 + tid;
        float s = dd_b1[j];
        #pragma unroll 8
        for (int k = 0; k < 256; ++k) s = fmaf(gmk[k], dd_w1[(size_t)(256 + k) * 512 + j], s);
        addvec[j] = s;
        return;
    }
    int wid = (blockIdx.x << 2) + (threadIdx.x >> 6);   // 0..2047
    int lane = threadIdx.x & 63;
    int mw = wid >> 6, nw = wid & 63;
    int m0 = mw << 5, n0 = nw << 5;
    int lr = lane & 15, quad = lane >> 4;
    const __hip_bfloat16* pa0 = A + (size_t)(m0 + lr) * DD + quad * 8;
    const __hip_bfloat16* pa1 = pa0 + 16 * DD;
    const __hip_bfloat16* pb0 = Bt + (size_t)(n0 + lr) * DD + quad * 8;
    const __hip_bfloat16* pb1 = pb0 + 16 * DD;
    f32x4 acc00 = {0,0,0,0}, acc01 = {0,0,0,0}, acc10 = {0,0,0,0}, acc11 = {0,0,0,0};
    #pragma unroll
    for (int k = 0; k < DD; k += 32) {
        short8 a0 = *(const short8*)(pa0 + k);
        short8 a1 = *(const short8*)(pa1 + k);
        short8 b0 = *(const short8*)(pb0 + k);
        short8 b1 = *(const short8*)(pb1 + k);
        acc00 = __builtin_amdgcn_mfma_f32_16x16x32_bf16(a0, b0, acc00, 0, 0, 0);
        acc01 = __builtin_amdgcn_mfma_f32_16x16x32_bf16(a0, b1, acc01, 0, 0, 0);
        acc10 = __builtin_amdgcn_mfma_f32_16x16x32_bf16(a1, b0, acc10, 0, 0, 0);
        acc11 = __builtin_amdgcn_mfma_f32_16x16x32_bf16(a1, b1, acc11, 0, 0, 0);
    }
    int col0 = n0 + lr, col1 = col0 + 16;
    float ip0 = 1.f / pn[col0], ip1 = 1.f / pn[col1];
    float cs0 = 0.f, cs1 = 0.f;
    #pragma unroll
    for (int r = 0; r < 4; ++r) {
        int row0 = m0 + quad * 4 + r;
        int row1 = row0 + 16;
        float if0 = 1.f / fn[row0];
        float if1 = 1.f / fn[row1];
        float d00 = 1.f - acc00[r] * if0 * ip0;
        float d01 = 1.f - acc01[r] * if0 * ip1;
        float d10 = 1.f - acc10[r] * if1 * ip0;
        float d11 = 1.f - acc11[r] * if1 * ip1;
        drift[(size_t)row0 * PP + col0] = d00;
        drift[(size_t)row0 * PP + col1] = d01;
        drift[(size_t)row1 * PP + col0] = d10;
        drift[(size_t)row1 * PP + col1] = d11;
        cs0 += d00 + d10;
        cs1 += d01 + d11;
    }
    cs0 += __shfl_xor(cs0, 16, 64); cs0 += __shfl_xor(cs0, 32, 64);
    cs1 += __shfl_xor(cs1, 16, 64); cs1 += __shfl_xor(cs1, 32, 64);
    if (quad == 0) {
        atomicAdd(&colsum[col0], cs0);
        atomicAdd(&colsum[col1], cs1);
    }
}

// ================ 32x32 MFMA tile device function ============================
template <int K, int OUT_BF16, int RELU>
__device__ __forceinline__ void gemm_tile(const __hip_bfloat16* __restrict__ A,
                                          const __hip_bfloat16* __restrict__ Bt,
                                          const float* __restrict__ bias0,
                                          const float* __restrict__ bias1, int split,
                                          void* __restrict__ Cout, int N, int lognt,
                                          int wid, int lane) {
    int mw = wid >> lognt, nw = wid & ((1 << lognt) - 1);
    int m0 = mw << 5, n0 = nw << 5;
    int lr = lane & 15, quad = lane >> 4;
    const __hip_bfloat16* pa0 = A + (size_t)(m0 + lr) * K + quad * 8;
    const __hip_bfloat16* pa1 = pa0 + 16 * K;
    const __hip_bfloat16* pb0 = Bt + (size_t)(n0 + lr) * K + quad * 8;
    const __hip_bfloat16* pb1 = pb0 + 16 * K;
    f32x4 acc00 = {0,0,0,0}, acc01 = {0,0,0,0}, acc10 = {0,0,0,0}, acc11 = {0,0,0,0};
    #pragma unroll
    for (int k = 0; k < K; k += 32) {
        short8 a0 = *(const short8*)(pa0 + k);
        short8 a1 = *(const short8*)(pa1 + k);
        short8 b0 = *(const short8*)(pb0 + k);
        short8 b1 = *(const short8*)(pb1 + k);
        acc00 = __builtin_amdgcn_mfma_f32_16x16x32_bf16(a0, b0, acc00, 0, 0, 0);
        acc01 = __builtin_amdgcn_mfma_f32_16x16x32_bf16(a0, b1, acc01, 0, 0, 0);
        acc10 = __builtin_amdgcn_mfma_f32_16x16x32_bf16(a1, b0, acc10, 0, 0, 0);
        acc11 = __builtin_amdgcn_mfma_f32_16x16x32_bf16(a1, b1, acc11, 0, 0, 0);
    }
    int col0 = n0 + lr, col1 = col0 + 16;
    float bi0 = (col0 < split) ? bias0[col0] : bias1[col0 - split];
    float bi1 = (col1 < split) ? bias0[col1] : bias1[col1 - split];
    #pragma unroll
    for (int r = 0; r < 4; ++r) {
        int row0 = m0 + quad * 4 + r;
        int row1 = row0 + 16;
        float v00 = acc00[r] + bi0, v01 = acc01[r] + bi1;
        float v10 = acc10[r] + bi0, v11 = acc11[r] + bi1;
        if (RELU) {
            v00 = fmaxf(v00, 0.f); v01 = fmaxf(v01, 0.f);
            v10 = fmaxf(v10, 0.f); v11 = fmaxf(v11, 0.f);
        }
        if (OUT_BF16) {
            __hip_bfloat16* C = (__hip_bfloat16*)Cout;
            C[(size_t)row0 * N + col0] = __float2bfloat16(v00);
            C[(size_t)row0 * N + col1] = __float2bfloat16(v01);
            C[(size_t)row1 * N + col0] = __float2bfloat16(v10);
            C[(size_t)row1 * N + col1] = __float2bfloat16(v11);
        } else {
            float* C = (float*)Cout;
            C[(size_t)row0 * N + col0] = v00;
            C[(size_t)row0 * N + col1] = v01;
            C[(size_t)row1 * N + col0] = v10;
            C[(size_t)row1 * N + col1] = v11;
        }
    }
}

// ================ K3: layer-1 GEMM for both MLPs (N=1024 concat) ==============
__global__ void gemm1_k(const __hip_bfloat16* __restrict__ pcb,
                        const __hip_bfloat16* __restrict__ w1cat,
                        const float* __restrict__ addvec, const float* __restrict__ cal_b1,
                        float* __restrict__ buf1) {
    int wid = (blockIdx.x << 2) + (threadIdx.x >> 6);
    gemm_tile<256, 0, 0>(pcb, w1cat, addvec, cal_b1, 512, buf1, 1024, 5,
                         wid, threadIdx.x & 63);
}

// ================ K4: dual layernorm+relu (512 | 512), fp32 -> bf16 ===========
__global__ void ln2_k(const float* __restrict__ X,
                      __hip_bfloat16* __restrict__ Ydd, __hip_bfloat16* __restrict__ Ycal,
                      const float* __restrict__ gdd, const float* __restrict__ bedd,
                      const float* __restrict__ gcal, const float* __restrict__ becal) {
    __shared__ float sm[4];
    int r = blockIdx.x, tid = threadIdx.x;
    const float* row = X + (size_t)r * 1024;
    // dd half (cols 0..511)
    {
        float x0 = row[tid], x1 = row[tid + 256];
        float mu = blk_reduce(x0 + x1, sm) * (1.f / HH);
        float d0 = x0 - mu, d1 = x1 - mu;
        float var = blk_reduce(d0 * d0 + d1 * d1, sm) * (1.f / HH);
        float rs = rsqrtf(var + 1e-5f);
        __hip_bfloat16* y = Ydd + (size_t)r * HH;
        y[tid]       = __float2bfloat16(fmaxf(d0 * rs * gdd[tid] + bedd[tid], 0.f));
        y[tid + 256] = __float2bfloat16(fmaxf(d1 * rs * gdd[tid + 256] + bedd[tid + 256], 0.f));
    }
    // cal half (cols 512..1023)
    {
        float x0 = row[512 + tid], x1 = row[768 + tid];
        float mu = blk_reduce(x0 + x1, sm) * (1.f / HH);
        float d0 = x0 - mu, d1 = x1 - mu;
        float var = blk_reduce(d0 * d0 + d1 * d1, sm) * (1.f / HH);
        float rs = rsqrtf(var + 1e-5f);
        __hip_bfloat16* y = Ycal + (size_t)r * HH;
        y[tid]       = __float2bfloat16(fmaxf(d0 * rs * gcal[tid] + becal[tid], 0.f));
        y[tid + 256] = __float2bfloat16(fmaxf(d1 * rs * gcal[tid + 256] + becal[tid + 256], 0.f));
    }
}

// ================ K5: dd2 + cal2 GEMMs, role by blockIdx ======================
__global__ void gemm2_k(const __hip_bfloat16* __restrict__ act_dd,
                        const __hip_bfloat16* __restrict__ act_cal,
                        const __hip_bfloat16* __restrict__ w2dd,
                        const __hip_bfloat16* __restrict__ w2cal,
                        const float* __restrict__ dd_b2, const float* __restrict__ cal_b2,
                        __hip_bfloat16* __restrict__ act2b, __hip_bfloat16* __restrict__ act3b) {
    int lane = threadIdx.x & 63;
    if (blockIdx.x < 128) {   // dd2: [2048,512]@[512,256] -> act2b
        int wid = (blockIdx.x << 2) + (threadIdx.x >> 6);
        gemm_tile<512, 1, 1>(act_dd, w2dd, dd_b2, dd_b2, 1 << 30, act2b, 256, 3, wid, lane);
    } else {                  // cal2: [2048,512]@[512,512] -> act3b
        int wid = ((blockIdx.x - 128) << 2) + (threadIdx.x >> 6);
        gemm_tile<512, 1, 1>(act_cal, w2cal, cal_b2, cal_b2, 1 << 30, act3b, 512, 4, wid, lane);
    }
}

// ================ K6: cal3 GEMM + conf/sigmoid/is_drifted =====================
__global__ void gemm3_conf_k(const __hip_bfloat16* __restrict__ act3b,
                             const __hip_bfloat16* __restrict__ w3cal,
                             const float* __restrict__ cal_b3,
                             const __hip_bfloat16* __restrict__ act2b,
                             const float* __restrict__ dd_w3, const float* __restrict__ dd_b3,
                             const float* __restrict__ colsum,
                             float* __restrict__ delta, float* __restrict__ strength,
                             float* __restrict__ out_is) {
    if (blockIdx.x < 128) {   // cal3: [2048,512]@[512,256] -> delta fp32
        int wid = (blockIdx.x << 2) + (threadIdx.x >> 6);
        gemm_tile<512, 0, 0>(act3b, w3cal, cal_b3, cal_b3, 1 << 30, delta, 256, 3,
                             wid, threadIdx.x & 63);
        return;
    }
    __shared__ float sm[4];
    int p = blockIdx.x - 128, tid = threadIdx.x;
    float v = __bfloat162float(act2b[(size_t)p * 256 + tid]) * dd_w3[tid];
    float s = blk_reduce(v, sm);
    if (tid == 0) {
        float conf = 1.f / (1.f + expf(-(s + dd_b3[0])));
        strength[p] = fminf(fmaxf(0.1f * conf, 0.f), 0.5f);
        out_is[p] = (colsum[p] * (1.f / BB) > 0.3f) ? 1.f : 0.f;
    }
}

// ================ K7: write calibrated [P,T,D], float4 ========================
__global__ void finalize_k(const float* __restrict__ pc, const float* __restrict__ delta,
                           const float* __restrict__ strength, const float* __restrict__ colsum,
                           const float* __restrict__ proto, float* __restrict__ out) {
    int p = blockIdx.x;
    int d4 = (threadIdx.x & 63) << 2;
    int t0 = threadIdx.x >> 6;
    bool dr = colsum[p] * (1.f / BB) > 0.3f;
    float* o = out + (size_t)p * TT * DD;
    if (dr) {
        float s = strength[p];
        float4 pcv = *(const float4*)(pc + (size_t)p * DD + d4);
        float4 dv  = *(const float4*)(delta + (size_t)p * DD + d4);
        float4 nc = make_float4(fmaf(s, dv.x, pcv.x), fmaf(s, dv.y, pcv.y),
                                fmaf(s, dv.z, pcv.z), fmaf(s, dv.w, pcv.w));
        #pragma unroll
        for (int t = t0; t < TT; t += 4)
            *(float4*)(o + t * DD + d4) = nc;
    } else {
        const float* pr = proto + (size_t)p * TT * DD;
        #pragma unroll
        for (int t = t0; t < TT; t += 4)
            *(float4*)(o + t * DD + d4) = *(const float4*)(pr + t * DD + d4);
    }
}

extern "C" void kernel_launch(void* const* d_in, const int* in_sizes, int n_in,
                              void* d_out, int out_size, void* d_ws, size_t ws_size,
                              hipStream_t stream) {
    const float* cf     = (const float*)d_in[0];
    const float* proto  = (const float*)d_in[1];
    const float* dd_w1  = (const float*)d_in[2];
    const float* dd_b1  = (const float*)d_in[3];
    const float* dd_g1  = (const float*)d_in[4];
    const float* dd_be1 = (const float*)d_in[5];
    const float* dd_w2  = (const float*)d_in[6];
    const float* dd_b2  = (const float*)d_in[7];
    const float* dd_w3  = (const float*)d_in[8];
    const float* dd_b3  = (const float*)d_in[9];
    const float* cal_w1 = (const float*)d_in[10];
    const float* cal_b1 = (const float*)d_in[11];
    const float* cal_g1 = (const float*)d_in[12];
    const float* cal_be1= (const float*)d_in[13];
    const float* cal_w2 = (const float*)d_in[14];
    const float* cal_b2 = (const float*)d_in[15];
    const float* cal_w3 = (const float*)d_in[16];
    const float* cal_b3 = (const float*)d_in[17];

    float* out_cal   = (float*)d_out;
    float* out_drift = out_cal + (size_t)PP * TT * DD;
    float* out_is    = out_drift + (size_t)BB * PP;

    float* w = (float*)d_ws;
    float* gmean8   = w;               // 2048 (8 copies x 256)
    float* colsum   = w + 2048;        // 2048
    float* addvec   = w + 4096;        // 512
    float* fn       = w + 4608;        // 1024
    float* pn       = w + 5632;        // 2048
    float* strength = w + 7680;        // 2048
    float* pc       = w + 9728;        // 2048*256
    float* buf1     = w + 534016;      // 2048*1024
    float* delta    = w + 2631168;     // 2048*256
    __hip_bfloat16* bb = (__hip_bfloat16*)(w + 3155456);
    __hip_bfloat16* ffb     = bb;                 // 1024*256
    __hip_bfloat16* pcb     = bb + 262144;        // 2048*256
    __hip_bfloat16* w1cat   = bb + 786432;        // 1024*256
    __hip_bfloat16* w2dd    = bb + 1048576;       // 256*512
    __hip_bfloat16* w2cal   = bb + 1179648;       // 512*512
    __hip_bfloat16* w3cal   = bb + 1441792;       // 256*512
    __hip_bfloat16* act_dd  = bb + 1572864;       // 2048*512
    __hip_bfloat16* act_cal = bb + 2621440;       // 2048*512
    __hip_bfloat16* act2b   = bb + 3670016;       // 2048*256
    __hip_bfloat16* act3b   = bb + 4194304;       // 2048*512

    hipMemsetAsync(d_ws, 0, 4096 * sizeof(float), stream);  // gmean8 + colsum

    prep_k<<<6144, 256, 0, stream>>>(cf, proto, dd_w1, dd_w2, cal_w1, cal_w2, cal_w3,
                                     gmean8, fn, pn, pc, ffb, pcb,
                                     w1cat, w2dd, w2cal, w3cal);
    sim_addvec_k<<<514, 256, 0, stream>>>(ffb, pcb, fn, pn, gmean8, dd_w1, dd_b1,
                                          out_drift, colsum, addvec);
    gemm1_k<<<512, 256, 0, stream>>>(pcb, w1cat, addvec, cal_b1, buf1);
    ln2_k<<<PP, 256, 0, stream>>>(buf1, act_dd, act_cal, dd_g1, dd_be1, cal_g1, cal_be1);
    gemm2_k<<<384, 256, 0, stream>>>(act_dd, act_cal, w2dd, w2cal, dd_b2, cal_b2,
                                     act2b, act3b);
    gemm3_conf_k<<<2176, 256, 0, stream>>>(act3b, w3cal, cal_b3, act2b, dd_w3, dd_b3,
                                           colsum, delta, strength, out_is);
    finalize_k<<<PP, 256, 0, stream>>>(pc, delta, strength, colsum, proto, out_cal);
}

// Round 5
// 415.681 us; speedup vs baseline: 1.2667x; 1.0053x over previous
//
#include <hip/hip_runtime.h>
#include <hip/hip_bf16.h>
#include <math.h>

#define BB 1024
#define TT 64
#define DD 256
#define PP 2048
#define HH 512

typedef __attribute__((ext_vector_type(8))) short short8;
typedef __attribute__((ext_vector_type(4))) float f32x4;

// ---------------- block reduction helper (256 threads) ----------------
__device__ __forceinline__ float blk_reduce(float v, float* sm) {
    int tid = threadIdx.x;
    #pragma unroll
    for (int o = 32; o > 0; o >>= 1) v += __shfl_down(v, o, 64);
    if ((tid & 63) == 0) sm[tid >> 6] = v;
    __syncthreads();
    float r = sm[0] + sm[1] + sm[2] + sm[3];
    __syncthreads();
    return r;
}

// ---------------- vectorized T-mean for one [64,256] row ----------------
// returns this thread's column mean m (column = tid), via float4 loads.
__device__ __forceinline__ float row_mean_vec(const float* __restrict__ base,
                                              float* __restrict__ smr) {
    int tid = threadIdx.x;
    int c4 = tid & 63;      // column group (4 cols)
    int t0 = tid >> 6;      // phase 0..3
    float4 s = make_float4(0.f, 0.f, 0.f, 0.f);
    #pragma unroll
    for (int t = t0; t < TT; t += 4) {
        float4 v = *(const float4*)(base + t * DD + (c4 << 2));
        s.x += v.x; s.y += v.y; s.z += v.z; s.w += v.w;
    }
    *(float4*)&smr[t0 * 256 + (c4 << 2)] = s;
    __syncthreads();
    float m = (smr[tid] + smr[256 + tid] + smr[512 + tid] + smr[768 + tid]) * (1.f / TT);
    __syncthreads();
    return m;
}

// ================ K1: prep — reductions + weight cvt, role by blockIdx ===========
__global__ void prep_k(const float* __restrict__ cf, const float* __restrict__ proto,
                       const float* __restrict__ dd_w1, const float* __restrict__ dd_w2,
                       const float* __restrict__ cal_w1, const float* __restrict__ cal_w2,
                       const float* __restrict__ cal_w3,
                       float* __restrict__ gmean8, float* __restrict__ fn,
                       float* __restrict__ pn, float* __restrict__ pc,
                       __hip_bfloat16* __restrict__ ffb, __hip_bfloat16* __restrict__ pcb,
                       __hip_bfloat16* __restrict__ w1cat, __hip_bfloat16* __restrict__ w2dd,
                       __hip_bfloat16* __restrict__ w2cal, __hip_bfloat16* __restrict__ w3cal) {
    __shared__ float smr[1024];
    __shared__ float sm[4];
    int b = blockIdx.x, tid = threadIdx.x;
    if (b < 1024) {                       // reduce current_feat row b
        float m = row_mean_vec(cf + (size_t)b * TT * DD, smr);
        ffb[(size_t)b * DD + tid] = __float2bfloat16(m);
        atomicAdd(&gmean8[(b & 7) * 256 + tid], m * (1.f / BB));
        float tot = blk_reduce(m * m, sm);
        if (tid == 0) fn[b] = fmaxf(sqrtf(tot), 1e-8f);
    } else if (b < 3072) {                // reduce prototype row
        int r = b - 1024;
        float m = row_mean_vec(proto + (size_t)r * TT * DD, smr);
        pc[(size_t)r * DD + tid] = m;
        pcb[(size_t)r * DD + tid] = __float2bfloat16(m);
        float tot = blk_reduce(m * m, sm);
        if (tid == 0) pn[r] = fmaxf(sqrtf(tot), 1e-8f);
    } else {                              // weight convert+transpose
        int idx = (b - 3072) * 256 + tid;
        if (idx < 262144) {               // w1cat: dd_w1 | cal_w1, K=256 N=512 each
            int half = idx >> 17;         // 0: dd, 1: cal
            int i = idx & 131071;
            int n = i & 511, k = i >> 9;
            const float* src = half ? cal_w1 : dd_w1;
            w1cat[(size_t)(half * 512 + n) * 256 + k] = __float2bfloat16(src[(size_t)k * 512 + n]);
        } else if (idx < 393216) {        // w2dd: K=512 N=256
            int i = idx - 262144;
            int n = i & 255, k = i >> 8;
            w2dd[(size_t)n * 512 + k] = __float2bfloat16(dd_w2[(size_t)k * 256 + n]);
        } else if (idx < 655360) {        // w2cal: K=512 N=512
            int i = idx - 393216;
            int n = i & 511, k = i >> 9;
            w2cal[(size_t)n * 512 + k] = __float2bfloat16(cal_w2[(size_t)k * 512 + n]);
        } else {                          // w3cal: K=512 N=256
            int i = idx - 655360;
            int n = i & 255, k = i >> 8;
            w3cal[(size_t)n * 512 + k] = __float2bfloat16(cal_w3[(size_t)k * 256 + n]);
        }
    }
}

// ================ K2: sim MFMA + addvec, role by blockIdx =====================
__global__ void sim_addvec_k(const __hip_bfloat16* __restrict__ A,
                             const __hip_bfloat16* __restrict__ Bt,
                             const float* __restrict__ fn, const float* __restrict__ pn,
                             const float* __restrict__ gmean8,
                             const float* __restrict__ dd_w1, const float* __restrict__ dd_b1,
                             float* __restrict__ drift, float* __restrict__ colsum,
                             float* __restrict__ addvec) {
    if (blockIdx.x >= 512) {              // addvec role: 2 blocks x 256 j's
        __shared__ float gmk[256];
        int tid = threadIdx.x;
        float g = 0.f;
        #pragma unroll
        for (int s = 0; s < 8; ++s) g += gmean8[s * 256 + tid];
        gmk[tid] = g;
        __syncthreads();
        int j = (blockIdx.x - 512) * 256 + tid;
        float s = dd_b1[j];
        #pragma unroll 8
        for (int k = 0; k < 256; ++k) s = fmaf(gmk[k], dd_w1[(size_t)(256 + k) * 512 + j], s);
        addvec[j] = s;
        return;
    }
    int wid = (blockIdx.x << 2) + (threadIdx.x >> 6);   // 0..2047
    int lane = threadIdx.x & 63;
    int mw = wid >> 6, nw = wid & 63;
    int m0 = mw << 5, n0 = nw << 5;
    int lr = lane & 15, quad = lane >> 4;
    const __hip_bfloat16* pa0 = A + (size_t)(m0 + lr) * DD + quad * 8;
    const __hip_bfloat16* pa1 = pa0 + 16 * DD;
    const __hip_bfloat16* pb0 = Bt + (size_t)(n0 + lr) * DD + quad * 8;
    const __hip_bfloat16* pb1 = pb0 + 16 * DD;
    f32x4 acc00 = {0,0,0,0}, acc01 = {0,0,0,0}, acc10 = {0,0,0,0}, acc11 = {0,0,0,0};
    #pragma unroll
    for (int k = 0; k < DD; k += 32) {
        short8 a0 = *(const short8*)(pa0 + k);
        short8 a1 = *(const short8*)(pa1 + k);
        short8 b0 = *(const short8*)(pb0 + k);
        short8 b1 = *(const short8*)(pb1 + k);
        acc00 = __builtin_amdgcn_mfma_f32_16x16x32_bf16(a0, b0, acc00, 0, 0, 0);
        acc01 = __builtin_amdgcn_mfma_f32_16x16x32_bf16(a0, b1, acc01, 0, 0, 0);
        acc10 = __builtin_amdgcn_mfma_f32_16x16x32_bf16(a1, b0, acc10, 0, 0, 0);
        acc11 = __builtin_amdgcn_mfma_f32_16x16x32_bf16(a1, b1, acc11, 0, 0, 0);
    }
    int col0 = n0 + lr, col1 = col0 + 16;
    float ip0 = 1.f / pn[col0], ip1 = 1.f / pn[col1];
    float cs0 = 0.f, cs1 = 0.f;
    #pragma unroll
    for (int r = 0; r < 4; ++r) {
        int row0 = m0 + quad * 4 + r;
        int row1 = row0 + 16;
        float if0 = 1.f / fn[row0];
        float if1 = 1.f / fn[row1];
        float d00 = 1.f - acc00[r] * if0 * ip0;
        float d01 = 1.f - acc01[r] * if0 * ip1;
        float d10 = 1.f - acc10[r] * if1 * ip0;
        float d11 = 1.f - acc11[r] * if1 * ip1;
        drift[(size_t)row0 * PP + col0] = d00;
        drift[(size_t)row0 * PP + col1] = d01;
        drift[(size_t)row1 * PP + col0] = d10;
        drift[(size_t)row1 * PP + col1] = d11;
        cs0 += d00 + d10;
        cs1 += d01 + d11;
    }
    cs0 += __shfl_xor(cs0, 16, 64); cs0 += __shfl_xor(cs0, 32, 64);
    cs1 += __shfl_xor(cs1, 16, 64); cs1 += __shfl_xor(cs1, 32, 64);
    if (quad == 0) {
        atomicAdd(&colsum[col0], cs0);
        atomicAdd(&colsum[col1], cs1);
    }
}

// ================ 32x32 MFMA tile device function ============================
template <int K, int OUT_BF16, int RELU>
__device__ __forceinline__ void gemm_tile(const __hip_bfloat16* __restrict__ A,
                                          const __hip_bfloat16* __restrict__ Bt,
                                          const float* __restrict__ bias0,
                                          const float* __restrict__ bias1, int split,
                                          void* __restrict__ Cout, int N, int lognt,
                                          int wid, int lane) {
    int mw = wid >> lognt, nw = wid & ((1 << lognt) - 1);
    int m0 = mw << 5, n0 = nw << 5;
    int lr = lane & 15, quad = lane >> 4;
    const __hip_bfloat16* pa0 = A + (size_t)(m0 + lr) * K + quad * 8;
    const __hip_bfloat16* pa1 = pa0 + 16 * K;
    const __hip_bfloat16* pb0 = Bt + (size_t)(n0 + lr) * K + quad * 8;
    const __hip_bfloat16* pb1 = pb0 + 16 * K;
    f32x4 acc00 = {0,0,0,0}, acc01 = {0,0,0,0}, acc10 = {0,0,0,0}, acc11 = {0,0,0,0};
    #pragma unroll
    for (int k = 0; k < K; k += 32) {
        short8 a0 = *(const short8*)(pa0 + k);
        short8 a1 = *(const short8*)(pa1 + k);
        short8 b0 = *(const short8*)(pb0 + k);
        short8 b1 = *(const short8*)(pb1 + k);
        acc00 = __builtin_amdgcn_mfma_f32_16x16x32_bf16(a0, b0, acc00, 0, 0, 0);
        acc01 = __builtin_amdgcn_mfma_f32_16x16x32_bf16(a0, b1, acc01, 0, 0, 0);
        acc10 = __builtin_amdgcn_mfma_f32_16x16x32_bf16(a1, b0, acc10, 0, 0, 0);
        acc11 = __builtin_amdgcn_mfma_f32_16x16x32_bf16(a1, b1, acc11, 0, 0, 0);
    }
    int col0 = n0 + lr, col1 = col0 + 16;
    float bi0 = (col0 < split) ? bias0[col0] : bias1[col0 - split];
    float bi1 = (col1 < split) ? bias0[col1] : bias1[col1 - split];
    #pragma unroll
    for (int r = 0; r < 4; ++r) {
        int row0 = m0 + quad * 4 + r;
        int row1 = row0 + 16;
        float v00 = acc00[r] + bi0, v01 = acc01[r] + bi1;
        float v10 = acc10[r] + bi0, v11 = acc11[r] + bi1;
        if (RELU) {
            v00 = fmaxf(v00, 0.f); v01 = fmaxf(v01, 0.f);
            v10 = fmaxf(v10, 0.f); v11 = fmaxf(v11, 0.f);
        }
        if (OUT_BF16) {
            __hip_bfloat16* C = (__hip_bfloat16*)Cout;
            C[(size_t)row0 * N + col0] = __float2bfloat16(v00);
            C[(size_t)row0 * N + col1] = __float2bfloat16(v01);
            C[(size_t)row1 * N + col0] = __float2bfloat16(v10);
            C[(size_t)row1 * N + col1] = __float2bfloat16(v11);
        } else {
            float* C = (float*)Cout;
            C[(size_t)row0 * N + col0] = v00;
            C[(size_t)row0 * N + col1] = v01;
            C[(size_t)row1 * N + col0] = v10;
            C[(size_t)row1 * N + col1] = v11;
        }
    }
}

// ================ K3: layer-1 GEMM for both MLPs (N=1024 concat) ==============
__global__ void gemm1_k(const __hip_bfloat16* __restrict__ pcb,
                        const __hip_bfloat16* __restrict__ w1cat,
                        const float* __restrict__ addvec, const float* __restrict__ cal_b1,
                        float* __restrict__ buf1) {
    int wid = (blockIdx.x << 2) + (threadIdx.x >> 6);
    gemm_tile<256, 0, 0>(pcb, w1cat, addvec, cal_b1, 512, buf1, 1024, 5,
                         wid, threadIdx.x & 63);
}

// ================ K4: dual layernorm+relu (512 | 512), fp32 -> bf16 ===========
__global__ void ln2_k(const float* __restrict__ X,
                      __hip_bfloat16* __restrict__ Ydd, __hip_bfloat16* __restrict__ Ycal,
                      const float* __restrict__ gdd, const float* __restrict__ bedd,
                      const float* __restrict__ gcal, const float* __restrict__ becal) {
    __shared__ float sm[4];
    int r = blockIdx.x, tid = threadIdx.x;
    const float* row = X + (size_t)r * 1024;
    // dd half (cols 0..511)
    {
        float x0 = row[tid], x1 = row[tid + 256];
        float mu = blk_reduce(x0 + x1, sm) * (1.f / HH);
        float d0 = x0 - mu, d1 = x1 - mu;
        float var = blk_reduce(d0 * d0 + d1 * d1, sm) * (1.f / HH);
        float rs = rsqrtf(var + 1e-5f);
        __hip_bfloat16* y = Ydd + (size_t)r * HH;
        y[tid]       = __float2bfloat16(fmaxf(d0 * rs * gdd[tid] + bedd[tid], 0.f));
        y[tid + 256] = __float2bfloat16(fmaxf(d1 * rs * gdd[tid + 256] + bedd[tid + 256], 0.f));
    }
    // cal half (cols 512..1023)
    {
        float x0 = row[512 + tid], x1 = row[768 + tid];
        float mu = blk_reduce(x0 + x1, sm) * (1.f / HH);
        float d0 = x0 - mu, d1 = x1 - mu;
        float var = blk_reduce(d0 * d0 + d1 * d1, sm) * (1.f / HH);
        float rs = rsqrtf(var + 1e-5f);
        __hip_bfloat16* y = Ycal + (size_t)r * HH;
        y[tid]       = __float2bfloat16(fmaxf(d0 * rs * gcal[tid] + becal[tid], 0.f));
        y[tid + 256] = __float2bfloat16(fmaxf(d1 * rs * gcal[tid + 256] + becal[tid + 256], 0.f));
    }
}

// ================ K5: dd2 + cal2 GEMMs, role by blockIdx ======================
__global__ void gemm2_k(const __hip_bfloat16* __restrict__ act_dd,
                        const __hip_bfloat16* __restrict__ act_cal,
                        const __hip_bfloat16* __restrict__ w2dd,
                        const __hip_bfloat16* __restrict__ w2cal,
                        const float* __restrict__ dd_b2, const float* __restrict__ cal_b2,
                        __hip_bfloat16* __restrict__ act2b, __hip_bfloat16* __restrict__ act3b) {
    int lane = threadIdx.x & 63;
    if (blockIdx.x < 128) {   // dd2: [2048,512]@[512,256] -> act2b
        int wid = (blockIdx.x << 2) + (threadIdx.x >> 6);
        gemm_tile<512, 1, 1>(act_dd, w2dd, dd_b2, dd_b2, 1 << 30, act2b, 256, 3, wid, lane);
    } else {                  // cal2: [2048,512]@[512,512] -> act3b
        int wid = ((blockIdx.x - 128) << 2) + (threadIdx.x >> 6);
        gemm_tile<512, 1, 1>(act_cal, w2cal, cal_b2, cal_b2, 1 << 30, act3b, 512, 4, wid, lane);
    }
}

// ================ K6: cal3 GEMM + conf/sigmoid/is_drifted =====================
__global__ void gemm3_conf_k(const __hip_bfloat16* __restrict__ act3b,
                             const __hip_bfloat16* __restrict__ w3cal,
                             const float* __restrict__ cal_b3,
                             const __hip_bfloat16* __restrict__ act2b,
                             const float* __restrict__ dd_w3, const float* __restrict__ dd_b3,
                             const float* __restrict__ colsum,
                             float* __restrict__ delta, float* __restrict__ strength,
                             float* __restrict__ out_is) {
    if (blockIdx.x < 128) {   // cal3: [2048,512]@[512,256] -> delta fp32
        int wid = (blockIdx.x << 2) + (threadIdx.x >> 6);
        gemm_tile<512, 0, 0>(act3b, w3cal, cal_b3, cal_b3, 1 << 30, delta, 256, 3,
                             wid, threadIdx.x & 63);
        return;
    }
    // conf role: one wave per p, blocks 128..639
    int p = ((blockIdx.x - 128) << 2) + (threadIdx.x >> 6);   // 0..2047
    int lane = threadIdx.x & 63;
    const __hip_bfloat16* row = act2b + (size_t)p * 256 + lane * 4;
    float s = 0.f;
    #pragma unroll
    for (int j = 0; j < 4; ++j)
        s += __bfloat162float(row[j]) * dd_w3[lane * 4 + j];
    #pragma unroll
    for (int o = 32; o > 0; o >>= 1) s += __shfl_down(s, o, 64);
    if (lane == 0) {
        float conf = 1.f / (1.f + expf(-(s + dd_b3[0])));
        strength[p] = fminf(fmaxf(0.1f * conf, 0.f), 0.5f);
        out_is[p] = (colsum[p] * (1.f / BB) > 0.3f) ? 1.f : 0.f;
    }
}

// ================ K7: write calibrated [P,T,D], float4 ========================
__global__ void finalize_k(const float* __restrict__ pc, const float* __restrict__ delta,
                           const float* __restrict__ strength, const float* __restrict__ colsum,
                           const float* __restrict__ proto, float* __restrict__ out) {
    int p = blockIdx.x;
    int d4 = (threadIdx.x & 63) << 2;
    int t0 = threadIdx.x >> 6;
    bool dr = colsum[p] * (1.f / BB) > 0.3f;
    float* o = out + (size_t)p * TT * DD;
    if (dr) {
        float s = strength[p];
        float4 pcv = *(const float4*)(pc + (size_t)p * DD + d4);
        float4 dv  = *(const float4*)(delta + (size_t)p * DD + d4);
        float4 nc = make_float4(fmaf(s, dv.x, pcv.x), fmaf(s, dv.y, pcv.y),
                                fmaf(s, dv.z, pcv.z), fmaf(s, dv.w, pcv.w));
        #pragma unroll
        for (int t = t0; t < TT; t += 4)
            *(float4*)(o + t * DD + d4) = nc;
    } else {
        const float* pr = proto + (size_t)p * TT * DD;
        #pragma unroll
        for (int t = t0; t < TT; t += 4)
            *(float4*)(o + t * DD + d4) = *(const float4*)(pr + t * DD + d4);
    }
}

extern "C" void kernel_launch(void* const* d_in, const int* in_sizes, int n_in,
                              void* d_out, int out_size, void* d_ws, size_t ws_size,
                              hipStream_t stream) {
    const float* cf     = (const float*)d_in[0];
    const float* proto  = (const float*)d_in[1];
    const float* dd_w1  = (const float*)d_in[2];
    const float* dd_b1  = (const float*)d_in[3];
    const float* dd_g1  = (const float*)d_in[4];
    const float* dd_be1 = (const float*)d_in[5];
    const float* dd_w2  = (const float*)d_in[6];
    const float* dd_b2  = (const float*)d_in[7];
    const float* dd_w3  = (const float*)d_in[8];
    const float* dd_b3  = (const float*)d_in[9];
    const float* cal_w1 = (const float*)d_in[10];
    const float* cal_b1 = (const float*)d_in[11];
    const float* cal_g1 = (const float*)d_in[12];
    const float* cal_be1= (const float*)d_in[13];
    const float* cal_w2 = (const float*)d_in[14];
    const float* cal_b2 = (const float*)d_in[15];
    const float* cal_w3 = (const float*)d_in[16];
    const float* cal_b3 = (const float*)d_in[17];

    float* out_cal   = (float*)d_out;
    float* out_drift = out_cal + (size_t)PP * TT * DD;
    float* out_is    = out_drift + (size_t)BB * PP;

    float* w = (float*)d_ws;
    float* gmean8   = w;               // 2048 (8 copies x 256)
    float* colsum   = w + 2048;        // 2048
    float* addvec   = w + 4096;        // 512
    float* fn       = w + 4608;        // 1024
    float* pn       = w + 5632;        // 2048
    float* strength = w + 7680;        // 2048
    float* pc       = w + 9728;        // 2048*256
    float* buf1     = w + 534016;      // 2048*1024
    float* delta    = w + 2631168;     // 2048*256
    __hip_bfloat16* bb = (__hip_bfloat16*)(w + 3155456);
    __hip_bfloat16* ffb     = bb;                 // 1024*256
    __hip_bfloat16* pcb     = bb + 262144;        // 2048*256
    __hip_bfloat16* w1cat   = bb + 786432;        // 1024*256
    __hip_bfloat16* w2dd    = bb + 1048576;       // 256*512
    __hip_bfloat16* w2cal   = bb + 1179648;       // 512*512
    __hip_bfloat16* w3cal   = bb + 1441792;       // 256*512
    __hip_bfloat16* act_dd  = bb + 1572864;       // 2048*512
    __hip_bfloat16* act_cal = bb + 2621440;       // 2048*512
    __hip_bfloat16* act2b   = bb + 3670016;       // 2048*256
    __hip_bfloat16* act3b   = bb + 4194304;       // 2048*512

    hipMemsetAsync(d_ws, 0, 4096 * sizeof(float), stream);  // gmean8 + colsum

    prep_k<<<6144, 256, 0, stream>>>(cf, proto, dd_w1, dd_w2, cal_w1, cal_w2, cal_w3,
                                     gmean8, fn, pn, pc, ffb, pcb,
                                     w1cat, w2dd, w2cal, w3cal);
    sim_addvec_k<<<514, 256, 0, stream>>>(ffb, pcb, fn, pn, gmean8, dd_w1, dd_b1,
                                          out_drift, colsum, addvec);
    gemm1_k<<<512, 256, 0, stream>>>(pcb, w1cat, addvec, cal_b1, buf1);
    ln2_k<<<PP, 256, 0, stream>>>(buf1, act_dd, act_cal, dd_g1, dd_be1, cal_g1, cal_be1);
    gemm2_k<<<384, 256, 0, stream>>>(act_dd, act_cal, w2dd, w2cal, dd_b2, cal_b2,
                                     act2b, act3b);
    gemm3_conf_k<<<640, 256, 0, stream>>>(act3b, w3cal, cal_b3, act2b, dd_w3, dd_b3,
                                          colsum, delta, strength, out_is);
    finalize_k<<<PP, 256, 0, stream>>>(pc, delta, strength, colsum, proto, out_cal);
}